// Round 4
// baseline (5957.121 us; speedup 1.0000x reference)
//
#include <hip/hip_runtime.h>

#define B_  16
#define T_  128
#define E_  300
#define EP_ 320
#define H_  1024
#define G3_ 3072
#define V_  32000

typedef __attribute__((ext_vector_type(8))) short short8;
typedef __attribute__((ext_vector_type(4))) float floatx4;
typedef __attribute__((ext_vector_type(4))) unsigned int uintx4;

// d_out offsets (elements, fp32): logits, style, content, mu_s, logvar_s, mu_c, logvar_c
#define OF_STYLE   65536000ull
#define OF_CONTENT 65537024ull
#define OF_MUS     65540096ull
#define OF_LVS     65541120ull
#define OF_MUC     65542144ull
#define OF_LVC     65545216ull

// Tag base in NaN-space: hbuf regions are recycled from bf16 weight buffers whose hi16
// bit-patterns are finite bf16 (incl. 0x0000 pad) -> never equal 0xFF00+t. Poison 0xAAAA too.
#define TAGB 0xFF00u
#define PK_TIMEOUT 1024
#define BULK_TRIES 64

__device__ __forceinline__ unsigned short f2bf(float f) {
  union { float f; unsigned u; } v; v.f = f;
  return (unsigned short)((v.u + 0x7fffu + ((v.u >> 16) & 1u)) >> 16);  // RNE
}

__device__ __forceinline__ float wsum(float v) {
  #pragma unroll
  for (int m = 1; m < 64; m <<= 1) v += __shfl_xor(v, m, 64);
  return v;
}

__device__ __forceinline__ float dot4(const float4 a, const float4 b) {
  return a.x * b.x + a.y * b.y + a.z * b.z + a.w * b.w;
}

__device__ __forceinline__ short8 cvt8(const float4 a, const float4 b) {
  short8 r;
  r[0] = (short)f2bf(a.x); r[1] = (short)f2bf(a.y);
  r[2] = (short)f2bf(a.z); r[3] = (short)f2bf(a.w);
  r[4] = (short)f2bf(b.x); r[5] = (short)f2bf(b.y);
  r[6] = (short)f2bf(b.z); r[7] = (short)f2bf(b.w);
  return r;
}

// CDNA vector L1 is write-through: ANY store reaches the XCD's shared L2 promptly.
// sc0 on loads = bypass/miss L1, service from L2 -> fast intra-XCD coherence point.
// sc1 (device scope) = LLC path -- fallback only.
__device__ __forceinline__ void st16_sc0(unsigned* addr, uintx4 v) {
  asm volatile("global_store_dwordx4 %0, %1, off sc0" :: "v"(addr), "v"(v) : "memory");
}
__device__ __forceinline__ void st16_sc1(unsigned* addr, uintx4 v) {
  asm volatile("global_store_dwordx4 %0, %1, off sc1" :: "v"(addr), "v"(v) : "memory");
}
__device__ __forceinline__ unsigned ldp_sc0(const unsigned* p) {
  unsigned v;
  // "=&v": dest must NOT alias the (loop-invariant) address pair.
  asm volatile("global_load_dword %0, %1, off sc0\n\t"
               "s_waitcnt vmcnt(0)" : "=&v"(v) : "v"(p) : "memory");
  return v;
}

// ---- Wih fp32 [3072][300] -> bf16 [3072][320] (zero-padded K) ----
__global__ void k_wih(const float* __restrict__ src, unsigned short* __restrict__ dst) {
  int idx = blockIdx.x * 256 + threadIdx.x;
  const int stride = gridDim.x * 256;
  for (; idx < G3_ * EP_; idx += stride) {
    int row = idx / EP_;
    int k = idx - row * EP_;
    dst[idx] = (k < E_) ? f2bf(src[row * E_ + k]) : (unsigned short)0;
  }
}

// ---- out_W fp32 [32000][1024] -> bf16 same layout (only when ws_size permits) ----
__global__ void k_cvtw(const float* __restrict__ src, unsigned short* __restrict__ dst, int n4) {
  int i = blockIdx.x * 256 + threadIdx.x;
  const int stride = gridDim.x * 256;
  for (; i < n4; i += stride) {
    float4 f = ((const float4*)src)[i];
    union { unsigned short us[4]; unsigned long long u; } pk;
    pk.us[0] = f2bf(f.x); pk.us[1] = f2bf(f.y); pk.us[2] = f2bf(f.z); pk.us[3] = f2bf(f.w);
    ((unsigned long long*)dst)[i] = pk.u;
  }
}

// ---- zero the gang-formation control blocks (every graph replay) ----
__global__ void k_ctl(int* c) { if (threadIdx.x < 32) c[threadIdx.x] = 0; }

// ---- embedding gather + LayerNorm -> e2[T][B][320] bf16 and shifted dec_e2 ----
__global__ void k_embed(const int* __restrict__ x, const int* __restrict__ sos,
                        const float* __restrict__ emb, const float* __restrict__ g,
                        const float* __restrict__ bta,
                        unsigned short* __restrict__ e2, unsigned short* __restrict__ de2) {
  const int row = blockIdx.x * 4 + (threadIdx.x >> 6);
  const int lane = threadIdx.x & 63;
  if (row > 2048) return;
  int tok, t = 0, b = 0;
  if (row < 2048) { b = row >> 7; t = row & 127; tok = x[row]; }
  else tok = sos[0];
  const float* src = emb + (size_t)tok * E_;
  float v[5]; float s = 0.f;
  #pragma unroll
  for (int i = 0; i < 5; ++i) { int k = lane + i * 64; v[i] = (k < E_) ? src[k] : 0.f; s += v[i]; }
  s = wsum(s);
  const float mu = s * (1.f / (float)E_);
  float q = 0.f;
  #pragma unroll
  for (int i = 0; i < 5; ++i) { int k = lane + i * 64; if (k < E_) { float d = v[i] - mu; q += d * d; } }
  q = wsum(q);
  const float rstd = rsqrtf(q * (1.f / (float)E_) + 1e-5f);
  #pragma unroll
  for (int i = 0; i < 5; ++i) {
    int k = lane + i * 64;  // 0..319
    unsigned short us = (k < E_) ? f2bf((v[i] - mu) * rstd * g[k] + bta[k]) : (unsigned short)0;
    if (row < 2048) {
      e2[(size_t)(t * 16 + b) * EP_ + k] = us;
      if (t < T_ - 1) de2[(size_t)((t + 1) * 16 + b) * EP_ + k] = us;
    } else {
      for (int bb = 0; bb < 16; ++bb) de2[(size_t)bb * EP_ + k] = us;  // dec_in[:,0,:] = LN(emb[sos])
    }
  }
}

// ---- xg = e @ Wih^T + bih : M=3072(g) N=2048(t*16+b) K=320.
// Output layout: xg[t][hc][b][3] fp32 (gate triple contiguous per (hc,b)) so the GRU
// loads all three gate pre-activations from one cache line (3 scalar dwords, 12B apart).
__global__ __launch_bounds__(256) void k_xg(const unsigned short* __restrict__ A,
                                            const unsigned short* __restrict__ Bm,
                                            const float* __restrict__ bih,
                                            float* __restrict__ xg) {
  __shared__ unsigned short lA[128 * 40];  // rows padded 32->40 bf16: 2-way-free LDS banks
  __shared__ unsigned short lB[128 * 40];
  const int tid = threadIdx.x;
  const int lane = tid & 63, wave = tid >> 6;
  const int wm = wave >> 1, wn = wave & 1;
  const int m0 = (blockIdx.x >> 4) * 128, n0 = (blockIdx.x & 15) * 128;
  floatx4 acc[4][4];
  #pragma unroll
  for (int i = 0; i < 4; ++i)
    #pragma unroll
    for (int jj = 0; jj < 4; ++jj) acc[i][jj] = (floatx4){0.f, 0.f, 0.f, 0.f};
  for (int kt = 0; kt < 10; ++kt) {
    const int k0 = kt * 32;
    __syncthreads();
    #pragma unroll
    for (int gi = 0; gi < 2; ++gi) {
      int gidx = tid + gi * 256;
      int r = gidx >> 2, kc = gidx & 3;
      short8 va = *(const short8*)(A + (size_t)(m0 + r) * EP_ + k0 + kc * 8);
      *(short8*)(&lA[r * 40 + kc * 8]) = va;
      short8 vb = *(const short8*)(Bm + (size_t)(n0 + r) * EP_ + k0 + kc * 8);
      *(short8*)(&lB[r * 40 + kc * 8]) = vb;
    }
    __syncthreads();
    short8 aF[4], bF[4];
    #pragma unroll
    for (int ms = 0; ms < 4; ++ms)
      aF[ms] = *(const short8*)(&lA[(wm * 64 + ms * 16 + (lane & 15)) * 40 + ((lane >> 4) << 3)]);
    #pragma unroll
    for (int ns = 0; ns < 4; ++ns)
      bF[ns] = *(const short8*)(&lB[(wn * 64 + ns * 16 + (lane & 15)) * 40 + ((lane >> 4) << 3)]);
    #pragma unroll
    for (int ms = 0; ms < 4; ++ms)
      #pragma unroll
      for (int ns = 0; ns < 4; ++ns)
        acc[ms][ns] = __builtin_amdgcn_mfma_f32_16x16x32_bf16(aF[ms], bF[ns], acc[ms][ns], 0, 0, 0);
  }
  #pragma unroll
  for (int ms = 0; ms < 4; ++ms) {
    const int mg0 = m0 + wm * 64 + ms * 16 + ((lane >> 4) << 2);
    #pragma unroll
    for (int ns = 0; ns < 4; ++ns) {
      const int nn = n0 + wn * 64 + ns * 16 + (lane & 15);
      const int tt = nn >> 4, bb = nn & 15;
      #pragma unroll
      for (int r = 0; r < 4; ++r) {
        const int mg = mg0 + r;
        const int tau = mg >> 10, hcw = mg & 1023;
        xg[(((size_t)tt * 1024 + hcw) * 16 + bb) * 3 + tau] = acc[ms][ns][r] + bih[mg];
      }
    }
  }
}

// ---- logits GEMM, fp32-B fallback (B converted fp32->bf16 inline) ----
__global__ __launch_bounds__(256) void k_final(const unsigned short* __restrict__ Ay,
                                               const float* __restrict__ Bw,
                                               const float* __restrict__ obias,
                                               float* __restrict__ out) {
  __shared__ unsigned short lA[128 * 40];
  __shared__ unsigned short lB[128 * 40];
  const int tid = threadIdx.x;
  const int lane = tid & 63, wave = tid >> 6;
  const int wm = wave >> 1, wn = wave & 1;
  const int m0 = (blockIdx.x & 15) * 128, n0 = (blockIdx.x >> 4) * 128;
  floatx4 acc[4][4];
  #pragma unroll
  for (int i = 0; i < 4; ++i)
    #pragma unroll
    for (int jj = 0; jj < 4; ++jj) acc[i][jj] = (floatx4){0.f, 0.f, 0.f, 0.f};
  for (int kt = 0; kt < 32; ++kt) {
    const int k0 = kt * 32;
    __syncthreads();
    #pragma unroll
    for (int gi = 0; gi < 2; ++gi) {
      int gidx = tid + gi * 256;
      int r = gidx >> 2, kc = gidx & 3;
      short8 va = *(const short8*)(Ay + (size_t)(m0 + r) * H_ + k0 + kc * 8);
      *(short8*)(&lA[r * 40 + kc * 8]) = va;
    }
    #pragma unroll
    for (int gi = 0; gi < 4; ++gi) {
      int gidx = tid + gi * 256;
      int r = gidx >> 3, kc = gidx & 7;
      float4 f = *(const float4*)(Bw + (size_t)(n0 + r) * H_ + k0 + kc * 4);
      union { unsigned short us[4]; unsigned long long u; } pk;
      pk.us[0] = f2bf(f.x); pk.us[1] = f2bf(f.y); pk.us[2] = f2bf(f.z); pk.us[3] = f2bf(f.w);
      *(unsigned long long*)(&lB[r * 40 + kc * 4]) = pk.u;
    }
    __syncthreads();
    short8 aF[4], bF[4];
    #pragma unroll
    for (int ms = 0; ms < 4; ++ms)
      aF[ms] = *(const short8*)(&lA[(wm * 64 + ms * 16 + (lane & 15)) * 40 + ((lane >> 4) << 3)]);
    #pragma unroll
    for (int ns = 0; ns < 4; ++ns)
      bF[ns] = *(const short8*)(&lB[(wn * 64 + ns * 16 + (lane & 15)) * 40 + ((lane >> 4) << 3)]);
    #pragma unroll
    for (int ms = 0; ms < 4; ++ms)
      #pragma unroll
      for (int ns = 0; ns < 4; ++ns)
        acc[ms][ns] = __builtin_amdgcn_mfma_f32_16x16x32_bf16(aF[ms], bF[ns], acc[ms][ns], 0, 0, 0);
  }
  #pragma unroll
  for (int ns = 0; ns < 4; ++ns) {
    const int nn = n0 + wn * 64 + ns * 16 + (lane & 15);
    const float bs = obias[nn];
    #pragma unroll
    for (int ms = 0; ms < 4; ++ms) {
      const int mm = m0 + wm * 64 + ms * 16 + ((lane >> 4) << 2);
      #pragma unroll
      for (int r = 0; r < 4; ++r)
        out[(size_t)(mm + r) * V_ + nn] = acc[ms][ns][r] + bs;
    }
  }
}

// ---- logits GEMM, pre-converted bf16 B ----
__global__ __launch_bounds__(256) void k_final_bf(const unsigned short* __restrict__ Ay,
                                                  const unsigned short* __restrict__ Bw,
                                                  const float* __restrict__ obias,
                                                  float* __restrict__ out) {
  __shared__ unsigned short lA[128 * 40];
  __shared__ unsigned short lB[128 * 40];
  const int tid = threadIdx.x;
  const int lane = tid & 63, wave = tid >> 6;
  const int wm = wave >> 1, wn = wave & 1;
  const int m0 = (blockIdx.x & 15) * 128, n0 = (blockIdx.x >> 4) * 128;  // m-fast: 16 blocks share B panel in L2
  floatx4 acc[4][4];
  #pragma unroll
  for (int i = 0; i < 4; ++i)
    #pragma unroll
    for (int jj = 0; jj < 4; ++jj) acc[i][jj] = (floatx4){0.f, 0.f, 0.f, 0.f};
  for (int kt = 0; kt < 32; ++kt) {
    const int k0 = kt * 32;
    __syncthreads();
    #pragma unroll
    for (int gi = 0; gi < 2; ++gi) {
      int gidx = tid + gi * 256;
      int r = gidx >> 2, kc = gidx & 3;
      short8 va = *(const short8*)(Ay + (size_t)(m0 + r) * H_ + k0 + kc * 8);
      *(short8*)(&lA[r * 40 + kc * 8]) = va;
      short8 vb = *(const short8*)(Bw + (size_t)(n0 + r) * H_ + k0 + kc * 8);
      *(short8*)(&lB[r * 40 + kc * 8]) = vb;
    }
    __syncthreads();
    short8 aF[4], bF[4];
    #pragma unroll
    for (int ms = 0; ms < 4; ++ms)
      aF[ms] = *(const short8*)(&lA[(wm * 64 + ms * 16 + (lane & 15)) * 40 + ((lane >> 4) << 3)]);
    #pragma unroll
    for (int ns = 0; ns < 4; ++ns)
      bF[ns] = *(const short8*)(&lB[(wn * 64 + ns * 16 + (lane & 15)) * 40 + ((lane >> 4) << 3)]);
    #pragma unroll
    for (int ms = 0; ms < 4; ++ms)
      #pragma unroll
      for (int ns = 0; ns < 4; ++ns)
        acc[ms][ns] = __builtin_amdgcn_mfma_f32_16x16x32_bf16(aF[ms], bF[ns], acc[ms][ns], 0, 0, 0);
  }
  #pragma unroll
  for (int ns = 0; ns < 4; ++ns) {
    const int nn = n0 + wn * 64 + ns * 16 + (lane & 15);
    const float bs = obias[nn];
    #pragma unroll
    for (int ms = 0; ms < 4; ++ms) {
      const int mm = m0 + wm * 64 + ms * 16 + ((lane >> 4) << 2);
      #pragma unroll
      for (int r = 0; r < 4; ++r)
        out[(size_t)(mm + r) * V_ + nn] = acc[ms][ns][r] + bs;
    }
  }
}

// ---- GRU recurrence: SINGLE-XCD GANG of 64 WGs, exchange through that XCD's L2.
// Launch 512 WGs (2/CU resident). Pigeonhole: >=505 incremented tickets => some XCD
// counter reaches 64; that XCD CASes itself winner; its ranks 0..63 are the gang (they
// exactly fill the XCD at 2 WG/CU); everyone else exits. Deadlock-free.
// Tagged dwords (r2-proven protocol) with sc0 stores/loads: write-through L1 -> data is
// in the XCD-shared L2 promptly; sc0 loads bypass L1 -> ~200-300cy RT vs ~2000cy LLC.
// Insurance (if the sc0 scope model is wrong): probe timeout / bulk-retry exhaustion =>
// republish last two packed publishes at device scope (sc1), raise panic flag, switch to
// agent-scope slow path (r2-proven). Others harvest panic every 16 steps. Since the whole
// gang is on ONE XCD, mixed fast/slow modes still see each other through the shared L2.
// hbuf layout (dwords): [buf2][row16=batch][col1024=h].
__global__ __launch_bounds__(256, 2) void k_gru(const float* __restrict__ xg,
                                                const float* __restrict__ Whh,
                                                const float* __restrict__ bhh,
                                                const float* __restrict__ h0,
                                                unsigned int* hbuf, int* ctl,
                                                float* __restrict__ hn_out,
                                                unsigned short* __restrict__ ys) {
  __shared__ float lred[2][3072];
  __shared__ int shctl[2];
  const int tid = threadIdx.x;
  const int lane = tid & 63, wave = tid >> 6;

  // ---- gang formation ----
  int xcd;
  asm volatile("s_getreg_b32 %0, hwreg(HW_REG_XCC_ID)" : "=s"(xcd));
  xcd &= 7;
  if (tid == 0) {
    int r = __hip_atomic_fetch_add(ctl + xcd, 1, __ATOMIC_RELAXED, __HIP_MEMORY_SCOPE_AGENT);
    shctl[0] = r;
    if (r == 63) {
      int expv = 0;
      __hip_atomic_compare_exchange_strong(ctl + 8, &expv, xcd + 1,
          __ATOMIC_RELAXED, __ATOMIC_RELAXED, __HIP_MEMORY_SCOPE_AGENT);
    }
    int wv;
    while ((wv = __hip_atomic_load(ctl + 8, __ATOMIC_RELAXED, __HIP_MEMORY_SCOPE_AGENT)) == 0)
      __builtin_amdgcn_s_sleep(2);
    shctl[1] = wv - 1;
  }
  __syncthreads();
  const int rank = shctl[0];
  if (shctl[1] != xcd || rank >= 64) return;   // not in the gang
  const int j = rank;                          // gang rank = owned column block

  const int b = tid & 15, c = tid >> 4;        // c = wave*4 + (lane>>4)
  const int hc = j * 16 + c;
  const int kbase = wave * 256;                // each wave covers a K-quarter
  int* panic = ctl + 9;

  #define REPUB() { if (lane < 16) { \
      unsigned* dd_ = hbuf + (size_t)lane * 1024 + j * 16 + wave * 4; \
      st16_sc1(dd_, pv0); st16_sc1(dd_ + 16384, pv1); } }

  // ---- publish h0 (tag TAGB) packed, sc1 insurance copy + sc0 fast copy ----
  float h_own = h0 ? h0[b * H_ + hc] : 0.f;
  uintx4 pv0, pv1;
  pv1[0] = pv1[1] = pv1[2] = pv1[3] = 0u;      // tag 0x0000: never matches
  {
    unsigned myd = (unsigned)f2bf(h_own) | (TAGB << 16);
    unsigned d1 = (unsigned)__shfl_xor((int)myd, 16, 64);
    unsigned long long pr = ((unsigned long long)d1 << 32) | myd;
    unsigned long long pr2 = (unsigned long long)__shfl_xor((long long)pr, 32, 64);
    uintx4 v; v[0] = (unsigned)pr; v[1] = (unsigned)(pr >> 32);
    v[2] = (unsigned)pr2; v[3] = (unsigned)(pr2 >> 32);
    pv0 = v;
    if (lane < 16) {
      unsigned* d0 = hbuf + (size_t)lane * 1024 + j * 16 + wave * 4;
      st16_sc1(d0, v);   // same value both scopes: any landing order is fine
      st16_sc0(d0, v);
    }
  }

  // ---- Whh B-fragments (fp32 -> bf16) into registers, once ----
  short8 bfrag[3][8];
  #pragma unroll
  for (int tau = 0; tau < 3; ++tau) {
    const float* wr = Whh + (size_t)(tau * H_ + j * 16 + (lane & 15)) * H_;
    #pragma unroll
    for (int s8 = 0; s8 < 8; ++s8) {
      int k = kbase + s8 * 32 + ((lane >> 4) << 3);
      float4 p0 = *(const float4*)(wr + k);
      float4 p1 = *(const float4*)(wr + k + 4);
      bfrag[tau][s8] = cvt8(p0, p1);
    }
  }
  const float bh0 = bhh[hc], bh1 = bhh[H_ + hc], bh2 = bhh[2 * H_ + hc];

  // xg base for this thread, layout [t][hc][b][3] fp32
  const float* xga = xg + ((size_t)hc * 16 + b) * 3;
  {  // warm step-0 line into local L2 (value unused; drained by first probe's vmcnt(0))
    unsigned xdum;
    asm volatile("global_load_dword %0, %1, off sc0" : "=&v"(xdum) : "v"(xga) : "memory");
  }

  // reader addresses (r2 mapping, verified)
  const int rrow = lane & 15;
  const int rcolb = kbase + ((lane >> 4) << 3);
  const unsigned long long* qbase =
      (const unsigned long long*)hbuf + ((size_t)rrow << 9) + (rcolb >> 1);
  const int pidx = ((lane >> 4) * 1028) + (wave * 16 + (lane & 15)) * 16;

  int mode = 0;
  for (int s = 0; s < T_; ++s) {
    const unsigned exp16 = TAGB + (unsigned)s;
    const size_t bufo = (size_t)(s & 1) << 14;  // dwords
    const unsigned* paddr = hbuf + bufo + pidx;

    // ---- PROBE ----
    if (mode == 0) {
      int it = 0;
      for (;;) {
        unsigned t = ldp_sc0(paddr);
        if (__all((t >> 16) == exp16)) break;
        if (++it >= PK_TIMEOUT) {
          mode = 1; REPUB();
          if (lane == 0)
            __hip_atomic_store(panic, 1, __ATOMIC_RELAXED, __HIP_MEMORY_SCOPE_AGENT);
          break;
        }
      }
      // periodic panic harvest (compiler emits proper waitcnt; off steady-state path)
      if (mode == 0 && (s & 15) == 15) {
        unsigned p = __hip_atomic_load((unsigned*)panic,
                                       __ATOMIC_RELAXED, __HIP_MEMORY_SCOPE_AGENT);
        if (p != 0) { mode = 1; REPUB(); }
      }
    }
    if (mode == 1) {
      for (;;) {
        unsigned t = __hip_atomic_load(paddr, __ATOMIC_RELAXED, __HIP_MEMORY_SCOPE_AGENT);
        if (__all((t >> 16) == exp16)) break;
        __builtin_amdgcn_s_sleep(1);
      }
    }
    __builtin_amdgcn_sched_barrier(0);

    // ---- BULK ----
    const char* src = (const char*)(qbase + (bufo >> 1));
    const float* xcur = xga + (size_t)s * 49152;
    const float* xnxt = xga + (size_t)(s < T_ - 1 ? s + 1 : s) * 49152;
    unsigned w[8][4];
    float fr, fz, fn;
    bool have = false;
    if (mode == 0) {
      int tries = 0;
      while (!have && tries < BULK_TRIES) {
        uintx4 qa0, qb0, qa1, qb1, qa2, qb2, qa3, qb3, qa4, qb4, qa5, qb5, qa6, qb6, qa7, qb7;
        unsigned dn;
        // 20 loads issued: 16 tag-quads, 3 xg dwords (12B apart, dword-aligned), 1
        // next-step L2-warm dword. vmcnt(4): oldest 16 (tags) complete (m135 semantics).
        asm volatile(
          "global_load_dwordx4 %0, %20, off sc0\n\t"
          "global_load_dwordx4 %1, %20, off offset:16 sc0\n\t"
          "global_load_dwordx4 %2, %20, off offset:128 sc0\n\t"
          "global_load_dwordx4 %3, %20, off offset:144 sc0\n\t"
          "global_load_dwordx4 %4, %20, off offset:256 sc0\n\t"
          "global_load_dwordx4 %5, %20, off offset:272 sc0\n\t"
          "global_load_dwordx4 %6, %20, off offset:384 sc0\n\t"
          "global_load_dwordx4 %7, %20, off offset:400 sc0\n\t"
          "global_load_dwordx4 %8, %20, off offset:512 sc0\n\t"
          "global_load_dwordx4 %9, %20, off offset:528 sc0\n\t"
          "global_load_dwordx4 %10, %20, off offset:640 sc0\n\t"
          "global_load_dwordx4 %11, %20, off offset:656 sc0\n\t"
          "global_load_dwordx4 %12, %20, off offset:768 sc0\n\t"
          "global_load_dwordx4 %13, %20, off offset:784 sc0\n\t"
          "global_load_dwordx4 %14, %20, off offset:896 sc0\n\t"
          "global_load_dwordx4 %15, %20, off offset:912 sc0\n\t"
          "global_load_dword %16, %21, off sc0\n\t"
          "global_load_dword %17, %21, off offset:4 sc0\n\t"
          "global_load_dword %18, %21, off offset:8 sc0\n\t"
          "global_load_dword %19, %22, off sc0\n\t"
          "s_waitcnt vmcnt(4)"
          : "=&v"(qa0), "=&v"(qb0), "=&v"(qa1), "=&v"(qb1),
            "=&v"(qa2), "=&v"(qb2), "=&v"(qa3), "=&v"(qb3),
            "=&v"(qa4), "=&v"(qb4), "=&v"(qa5), "=&v"(qb5),
            "=&v"(qa6), "=&v"(qb6), "=&v"(qa7), "=&v"(qb7),
            "=&v"(fr), "=&v"(fz), "=&v"(fn), "=&v"(dn)
          : "v"(src), "v"(xcur), "v"(xnxt)
          : "memory");
        __builtin_amdgcn_sched_barrier(0);
        unsigned ok = 1u;
        #define VPK(qa_, qb_, s8_) { \
          ok &= (unsigned)((qa_[0] >> 16) == exp16) & (unsigned)((qa_[1] >> 16) == exp16) & \
                (unsigned)((qa_[2] >> 16) == exp16) & (unsigned)((qa_[3] >> 16) == exp16) & \
                (unsigned)((qb_[0] >> 16) == exp16) & (unsigned)((qb_[1] >> 16) == exp16) & \
                (unsigned)((qb_[2] >> 16) == exp16) & (unsigned)((qb_[3] >> 16) == exp16);  \
          w[s8_][0] = (qa_[0] & 0xffffu) | (qa_[1] << 16); \
          w[s8_][1] = (qa_[2] & 0xffffu) | (qa_[3] << 16); \
          w[s8_][2] = (qb_[0] & 0xffffu) | (qb_[1] << 16); \
          w[s8_][3] = (qb_[2] & 0xffffu) | (qb_[3] << 16); }
        VPK(qa0, qb0, 0) VPK(qa1, qb1, 1) VPK(qa2, qb2, 2) VPK(qa3, qb3, 3)
        VPK(qa4, qb4, 4) VPK(qa5, qb5, 5) VPK(qa6, qb6, 6) VPK(qa7, qb7, 7)
        #undef VPK
        have = __all(ok != 0u);
        ++tries;
      }
      if (!have) {
        mode = 1; REPUB();
        if (lane == 0)
          __hip_atomic_store(panic, 1, __ATOMIC_RELAXED, __HIP_MEMORY_SCOPE_AGENT);
      }
    }
    if (!have) {
      // slow path (agent scope, r2-proven); same-XCD L2 still services these
      const unsigned long long* sq = (const unsigned long long*)src;
      const unsigned long long expq =
          ((unsigned long long)exp16 << 16) | ((unsigned long long)exp16 << 48);
      unsigned long long q[8][4];
      for (;;) {
        bool okk = true;
        #pragma unroll
        for (int s8 = 0; s8 < 8; ++s8)
          #pragma unroll
          for (int p = 0; p < 4; ++p) {
            q[s8][p] = __hip_atomic_load(sq + s8 * 16 + p,
                                         __ATOMIC_RELAXED, __HIP_MEMORY_SCOPE_AGENT);
            okk &= ((q[s8][p] & 0xFFFF0000FFFF0000ull) == expq);
          }
        if (__all(okk)) break;
        __builtin_amdgcn_s_sleep(1);
      }
      #pragma unroll
      for (int s8 = 0; s8 < 8; ++s8)
        #pragma unroll
        for (int p = 0; p < 4; ++p)
          w[s8][p] = (unsigned)(q[s8][p] & 0xffffu) |
                     ((unsigned)(q[s8][p] >> 16) & 0xffff0000u);
      fr = xcur[0]; fz = xcur[1]; fn = xcur[2];
    }

    // ---- MFMA ----
    floatx4 a0 = {0.f,0.f,0.f,0.f}, a1 = {0.f,0.f,0.f,0.f}, a2 = {0.f,0.f,0.f,0.f};
    #pragma unroll
    for (int s8 = 0; s8 < 8; ++s8) {
      union { unsigned u[4]; short8 v; } uu;
      uu.u[0] = w[s8][0]; uu.u[1] = w[s8][1]; uu.u[2] = w[s8][2]; uu.u[3] = w[s8][3];
      a0 = __builtin_amdgcn_mfma_f32_16x16x32_bf16(uu.v, bfrag[0][s8], a0, 0, 0, 0);
      a1 = __builtin_amdgcn_mfma_f32_16x16x32_bf16(uu.v, bfrag[1][s8], a1, 0, 0, 0);
      a2 = __builtin_amdgcn_mfma_f32_16x16x32_bf16(uu.v, bfrag[2][s8], a2, 0, 0, 0);
    }
    float* lr = lred[s & 1];
    {
      int pb = wave * 768 + (lane & 15) * 16 + ((lane >> 4) << 2);
      *(floatx4*)(&lr[pb])       = a0;
      *(floatx4*)(&lr[pb + 256]) = a1;
      *(floatx4*)(&lr[pb + 512]) = a2;
    }
    // raw barrier: wait LDS only; vmem (xg gates / prefetch) stays in flight
    __builtin_amdgcn_sched_barrier(0);
    asm volatile("s_waitcnt lgkmcnt(0)" ::: "memory");
    __builtin_amdgcn_s_barrier();
    __builtin_amdgcn_sched_barrier(0);
    float g0 = bh0, g1 = bh1, g2 = bh2;
    #pragma unroll
    for (int wv = 0; wv < 4; ++wv) {
      int rb = wv * 768 + c * 16 + b;
      g0 += lr[rb]; g1 += lr[rb + 256]; g2 += lr[rb + 512];
    }
    // fast path: oldest 19 of 20 complete -> fr/fz/fn valid (only warm-dword outstanding)
    if (mode == 0) { asm volatile("s_waitcnt vmcnt(1)" ::: "memory"); }
    __builtin_amdgcn_sched_barrier(0);
    const float rg = 1.f / (1.f + expf(-(fr + g0)));
    const float zg = 1.f / (1.f + expf(-(fz + g1)));
    const float ng = tanhf(fn + rg * g2);
    const float hnew = (1.f - zg) * ng + zg * h_own;
    h_own = hnew;
    // ---- publish (critical path): pack 4 tagged cols -> one 16B sc0 store ----
    {
      unsigned myd = (unsigned)f2bf(hnew) | ((TAGB + (unsigned)(s + 1)) << 16);
      unsigned d1 = (unsigned)__shfl_xor((int)myd, 16, 64);
      unsigned long long pr = ((unsigned long long)d1 << 32) | myd;
      unsigned long long pr2 = (unsigned long long)__shfl_xor((long long)pr, 32, 64);
      uintx4 v; v[0] = (unsigned)pr; v[1] = (unsigned)(pr >> 32);
      v[2] = (unsigned)pr2; v[3] = (unsigned)(pr2 >> 32);
      if (((s + 1) & 1) == 0) pv0 = v; else pv1 = v;
      if (lane < 16) {
        unsigned* dst = hbuf + (((size_t)((s + 1) & 1)) << 14) +
                        (size_t)lane * 1024 + j * 16 + wave * 4;
        st16_sc0(dst, v);
        if (mode) st16_sc1(dst, v);
      }
    }
    if (ys) ys[(size_t)(b * T_ + s) * H_ + hc] = f2bf(hnew);
  }
  if (hn_out) hn_out[b * H_ + hc] = h_own;
  #undef REPUB
}

// ---- VAE heads: mu/logvar/style/content (+ cat buffer for fc). One wave per (b,o). ----
__global__ void k_heads(const float* __restrict__ hn,
                        const float* __restrict__ musW, const float* __restrict__ musb,
                        const float* __restrict__ varsW, const float* __restrict__ varsb,
                        const float* __restrict__ mucW, const float* __restrict__ mucb,
                        const float* __restrict__ varcW, const float* __restrict__ varcb,
                        const float* __restrict__ eps_s, const float* __restrict__ eps_c,
                        float* __restrict__ out, float* __restrict__ cat) {
  const int wv = blockIdx.x * 4 + (threadIdx.x >> 6);
  const int lane = threadIdx.x & 63;
  const int b = wv >> 8, o = wv & 255;
  const float* h = hn + (size_t)b * H_;
  const float *w1, *w2; float bb1, bb2, ep; int oc = 0;
  const int smode = (o < 64);
  if (smode) { w1 = musW + (size_t)o * H_;  w2 = varsW + (size_t)o * H_;  bb1 = musb[o];  bb2 = varsb[o];  ep = eps_s[b * 64 + o]; }
  else { oc = o - 64; w1 = mucW + (size_t)oc * H_; w2 = varcW + (size_t)oc * H_; bb1 = mucb[oc]; bb2 = varcb[oc]; ep = eps_c[b * 192 + oc]; }
  float s1 = 0.f, s2 = 0.f;
  #pragma unroll
  for (int i = 0; i < 4; ++i) {
    int k = lane * 4 + i * 256;
    float4 hv = *(const float4*)(h + k);
    float4 av = *(const float4*)(w1 + k);
    float4 bv = *(const float4*)(w2 + k);
    s1 += dot4(hv, av); s2 += dot4(hv, bv);
  }
  s1 = wsum(s1); s2 = wsum(s2);
  if (lane == 0) {
    const float mu = s1 + bb1, lv = s2 + bb2;
    const float sc = mu + ep * expf(0.5f * lv);
    if (smode) {
      out[OF_MUS + b * 64 + o] = mu;
      out[OF_LVS + b * 64 + o] = lv;
      out[OF_STYLE + b * 64 + o] = sc;
      cat[b * 256 + o] = sc;
    } else {
      out[OF_MUC + b * 192 + oc] = mu;
      out[OF_LVC + b * 192 + oc] = lv;
      out[OF_CONTENT + b * 192 + oc] = sc;
      cat[b * 256 + 64 + oc] = sc;
    }
  }
}

// ---- z = cat @ fc_W^T + fc_b : one wave per (b,h), K=256 = 64 lanes x float4 ----
__global__ void k_z(const float* __restrict__ cat, const float* __restrict__ fcW,
                    const float* __restrict__ fcb, float* __restrict__ z) {
  const int wv = blockIdx.x * 4 + (threadIdx.x >> 6);
  const int lane = threadIdx.x & 63;
  const int b = wv >> 10, h = wv & 1023;
  float4 a = *(const float4*)(cat + b * 256 + lane * 4);
  float4 w = *(const float4*)(fcW + (size_t)h * 256 + lane * 4);
  float p = dot4(a, w);
  p = wsum(p);
  if (lane == 0) z[b * H_ + h] = p + fcb[h];
}

extern "C" void kernel_launch(void* const* d_in, const int* in_sizes, int n_in,
                              void* d_out, int out_size, void* d_ws, size_t ws_size,
                              hipStream_t stream) {
  (void)in_sizes; (void)n_in; (void)out_size;
  const int*   x       = (const int*)d_in[0];
  const int*   sos     = (const int*)d_in[1];
  const float* eps_s   = (const float*)d_in[2];
  const float* eps_c   = (const float*)d_in[3];
  const float* emb     = (const float*)d_in[4];
  const float* ln_g    = (const float*)d_in[5];
  const float* ln_b    = (const float*)d_in[6];
  const float* enc_Wih = (const float*)d_in[7];
  const float* enc_Whh = (const float*)d_in[8];
  const float* enc_bih = (const float*)d_in[9];
  const float* enc_bhh = (const float*)d_in[10];
  const float* mus_W   = (const float*)d_in[11];
  const float* mus_b   = (const float*)d_in[12];
  const float* vars_W  = (const float*)d_in[13];
  const float* vars_b  = (const float*)d_in[14];
  const float* muc_W   = (const float*)d_in[15];
  const float* muc_b   = (const float*)d_in[16];
  const float* varc_W  = (const float*)d_in[17];
  const float* varc_b  = (const float*)d_in[18];
  const float* fc_W    = (const float*)d_in[19];
  const float* fc_b    = (const float*)d_in[20];
  const float* dec_Wih = (const float*)d_in[21];
  const float* dec_Whh = (const float*)d_in[22];
  const float* dec_bih = (const float*)d_in[23];
  const float* dec_bhh = (const float*)d_in[24];
  const float* out_W   = (const float*)d_in[25];
  const float* out_b   = (const float*)d_in[26];
  float* out = (float*)d_out;

  char* w = (char*)d_ws;
  unsigned short* e2   = (unsigned short*)(w + 0);          // 1,310,720
  unsigned short* de2  = (unsigned short*)(w + 1310720);    // 1,310,720
  unsigned short* wihE = (unsigned short*)(w + 2621440);    // 1,966,080
  unsigned short* wihD = (unsigned short*)(w + 4587520);    // 1,966,080
  float* xgE           = (float*)(w + 6553600);             // 25,165,824
  float* xgD           = (float*)(w + 31719424);            // 25,165,824
  unsigned short* ys   = (unsigned short*)(w + 56885248);   // 4,194,304
  float* hn            = (float*)(w + 61145088);            // 65,536
  float* zb            = (float*)(w + 61210624);            // 65,536
  float* catb          = (float*)(w + 61276160);            // 16,384
  int* ctl             = (int*)(w + 61292544);              // 128 B (2 x 16 ints), re-zeroed by k_ctl
  unsigned short* woutBf = (unsigned short*)(w + 61293056); // 65,536,000 (optional)
  // Tagged h-state buffers live in the (dead-by-then) wihE region: wihE is only read by
  // k_xg(E), which completes before k_gru(E) launches (stream-ordered). Contents there are
  // finite bf16 weights (incl. exact-zero K-pad) whose hi16 can never equal NaN-space tags,
  // and k_wih rewrites the whole region on every graph replay before the GRUs run.
  unsigned int* hbufE  = (unsigned int*)(w + 2621440);             // 131,072 (2 x 16 x 1024 dwords)
  unsigned int* hbufD  = (unsigned int*)(w + 2621440 + 131072);    // 131,072
  int* ctlE = ctl;
  int* ctlD = ctl + 16;
  const bool bigws = (ws_size >= 126829056ull);

  k_ctl<<<1, 64, 0, stream>>>(ctl);
  k_wih<<<960, 256, 0, stream>>>(enc_Wih, wihE);
  k_wih<<<960, 256, 0, stream>>>(dec_Wih, wihD);
  if (bigws) k_cvtw<<<2048, 256, 0, stream>>>(out_W, woutBf, V_ * H_ / 4);
  k_embed<<<513, 256, 0, stream>>>(x, sos, emb, ln_g, ln_b, e2, de2);
  k_xg<<<384, 256, 0, stream>>>(wihE, e2, enc_bih, xgE);
  k_xg<<<384, 256, 0, stream>>>(wihD, de2, dec_bih, xgD);
  k_gru<<<512, 256, 0, stream>>>(xgE, enc_Whh, enc_bhh, (const float*)nullptr,
                                 hbufE, ctlE, hn, (unsigned short*)nullptr);
  k_heads<<<1024, 256, 0, stream>>>(hn, mus_W, mus_b, vars_W, vars_b,
                                    muc_W, muc_b, varc_W, varc_b, eps_s, eps_c, out, catb);
  k_z<<<4096, 256, 0, stream>>>(catb, fc_W, fc_b, zb);
  k_gru<<<512, 256, 0, stream>>>(xgD, dec_Whh, dec_bhh, zb,
                                 hbufD, ctlD, (float*)nullptr, ys);
  if (bigws) k_final_bf<<<4000, 256, 0, stream>>>(ys, woutBf, out_b, out);
  else       k_final<<<4000, 256, 0, stream>>>(ys, out_W, out_b, out);
}

// Round 5
// 1816.279 us; speedup vs baseline: 3.2798x; 3.2798x over previous
//
#include <hip/hip_runtime.h>

#define B_  16
#define T_  128
#define E_  300
#define EP_ 320
#define H_  1024
#define G3_ 3072
#define V_  32000

typedef __attribute__((ext_vector_type(8))) short short8;
typedef __attribute__((ext_vector_type(4))) float floatx4;

// d_out offsets (elements, fp32): logits, style, content, mu_s, logvar_s, mu_c, logvar_c
#define OF_STYLE   65536000ull
#define OF_CONTENT 65537024ull
#define OF_MUS     65540096ull
#define OF_LVS     65541120ull
#define OF_MUC     65542144ull
#define OF_LVC     65545216ull

__device__ __forceinline__ unsigned short f2bf(float f) {
  union { float f; unsigned u; } v; v.f = f;
  return (unsigned short)((v.u + 0x7fffu + ((v.u >> 16) & 1u)) >> 16);  // RNE
}

__device__ __forceinline__ float wsum(float v) {
  #pragma unroll
  for (int m = 1; m < 64; m <<= 1) v += __shfl_xor(v, m, 64);
  return v;
}

__device__ __forceinline__ float dot4(const float4 a, const float4 b) {
  return a.x * b.x + a.y * b.y + a.z * b.z + a.w * b.w;
}

__device__ __forceinline__ short8 cvt8(const float4 a, const float4 b) {
  short8 r;
  r[0] = (short)f2bf(a.x); r[1] = (short)f2bf(a.y);
  r[2] = (short)f2bf(a.z); r[3] = (short)f2bf(a.w);
  r[4] = (short)f2bf(b.x); r[5] = (short)f2bf(b.y);
  r[6] = (short)f2bf(b.z); r[7] = (short)f2bf(b.w);
  return r;
}

// Device-scope (sc1) 2B store: bypasses the writer XCD's L2, lands at the LLC so
// same-kernel readers on OTHER XCDs see it (ys -> fused logits-GEMM blocks).
__device__ __forceinline__ void st2_sc1(unsigned short* p, unsigned short v) {
  asm volatile("global_store_short %0, %1, off sc1" :: "v"(p), "v"((unsigned)v) : "memory");
}

// ---- Wih fp32 [3072][300] -> bf16 [3072][320] (zero-padded K) ----
__global__ void k_wih(const float* __restrict__ src, unsigned short* __restrict__ dst) {
  int idx = blockIdx.x * 256 + threadIdx.x;
  const int stride = gridDim.x * 256;
  for (; idx < G3_ * EP_; idx += stride) {
    int row = idx / EP_;
    int k = idx - row * EP_;
    dst[idx] = (k < E_) ? f2bf(src[row * E_ + k]) : (unsigned short)0;
  }
}

// ---- embedding gather + LayerNorm -> e2[T][B][320] bf16 and shifted dec_e2 ----
__global__ void k_embed(const int* __restrict__ x, const int* __restrict__ sos,
                        const float* __restrict__ emb, const float* __restrict__ g,
                        const float* __restrict__ bta,
                        unsigned short* __restrict__ e2, unsigned short* __restrict__ de2) {
  const int row = blockIdx.x * 4 + (threadIdx.x >> 6);
  const int lane = threadIdx.x & 63;
  if (row > 2048) return;
  int tok, t = 0, b = 0;
  if (row < 2048) { b = row >> 7; t = row & 127; tok = x[row]; }
  else tok = sos[0];
  const float* src = emb + (size_t)tok * E_;
  float v[5]; float s = 0.f;
  #pragma unroll
  for (int i = 0; i < 5; ++i) { int k = lane + i * 64; v[i] = (k < E_) ? src[k] : 0.f; s += v[i]; }
  s = wsum(s);
  const float mu = s * (1.f / (float)E_);
  float q = 0.f;
  #pragma unroll
  for (int i = 0; i < 5; ++i) { int k = lane + i * 64; if (k < E_) { float d = v[i] - mu; q += d * d; } }
  q = wsum(q);
  const float rstd = rsqrtf(q * (1.f / (float)E_) + 1e-5f);
  #pragma unroll
  for (int i = 0; i < 5; ++i) {
    int k = lane + i * 64;  // 0..319
    unsigned short us = (k < E_) ? f2bf((v[i] - mu) * rstd * g[k] + bta[k]) : (unsigned short)0;
    if (row < 2048) {
      e2[(size_t)(t * 16 + b) * EP_ + k] = us;
      if (t < T_ - 1) de2[(size_t)((t + 1) * 16 + b) * EP_ + k] = us;
    } else {
      for (int bb = 0; bb < 16; ++bb) de2[(size_t)bb * EP_ + k] = us;  // dec_in[:,0,:] = LN(emb[sos])
    }
  }
}

// ---- xg GEMM body: xg = e @ Wih^T + bih, out xg[T][3H][B] fp32 (r0 layout) ----
__device__ __forceinline__ void xg_body(const int bid,
                                        const unsigned short* __restrict__ A,
                                        const unsigned short* __restrict__ Bm,
                                        const float* __restrict__ bih,
                                        float* __restrict__ xg,
                                        unsigned short* lA, unsigned short* lB,
                                        const int tid) {
  const int lane = tid & 63, wave = tid >> 6;
  const int wm = wave >> 1, wn = wave & 1;
  const int m0 = (bid >> 4) * 128, n0 = (bid & 15) * 128;
  floatx4 acc[4][4];
  #pragma unroll
  for (int i = 0; i < 4; ++i)
    #pragma unroll
    for (int jj = 0; jj < 4; ++jj) acc[i][jj] = (floatx4){0.f, 0.f, 0.f, 0.f};
  for (int kt = 0; kt < 10; ++kt) {
    const int k0 = kt * 32;
    __syncthreads();
    #pragma unroll
    for (int gi = 0; gi < 2; ++gi) {
      int gidx = tid + gi * 256;
      int r = gidx >> 2, kc = gidx & 3;
      short8 va = *(const short8*)(A + (size_t)(m0 + r) * EP_ + k0 + kc * 8);
      *(short8*)(&lA[r * 40 + kc * 8]) = va;
      short8 vb = *(const short8*)(Bm + (size_t)(n0 + r) * EP_ + k0 + kc * 8);
      *(short8*)(&lB[r * 40 + kc * 8]) = vb;
    }
    __syncthreads();
    short8 aF[4], bF[4];
    #pragma unroll
    for (int ms = 0; ms < 4; ++ms)
      aF[ms] = *(const short8*)(&lA[(wm * 64 + ms * 16 + (lane & 15)) * 40 + ((lane >> 4) << 3)]);
    #pragma unroll
    for (int ns = 0; ns < 4; ++ns)
      bF[ns] = *(const short8*)(&lB[(wn * 64 + ns * 16 + (lane & 15)) * 40 + ((lane >> 4) << 3)]);
    #pragma unroll
    for (int ms = 0; ms < 4; ++ms)
      #pragma unroll
      for (int ns = 0; ns < 4; ++ns)
        acc[ms][ns] = __builtin_amdgcn_mfma_f32_16x16x32_bf16(aF[ms], bF[ns], acc[ms][ns], 0, 0, 0);
  }
  #pragma unroll
  for (int ms = 0; ms < 4; ++ms) {
    const int mg0 = m0 + wm * 64 + ms * 16 + ((lane >> 4) << 2);
    #pragma unroll
    for (int ns = 0; ns < 4; ++ns) {
      const int nn = n0 + wn * 64 + ns * 16 + (lane & 15);
      const int tt = nn >> 4, bb = nn & 15;
      #pragma unroll
      for (int r = 0; r < 4; ++r)
        xg[(size_t)tt * (G3_ * 16) + (size_t)(mg0 + r) * 16 + bb] = acc[ms][ns][r] + bih[mg0 + r];
    }
  }
}

__global__ __launch_bounds__(256) void k_xg(const unsigned short* __restrict__ A,
                                            const unsigned short* __restrict__ Bm,
                                            const float* __restrict__ bih,
                                            float* __restrict__ xg) {
  __shared__ unsigned short lA[128 * 40];
  __shared__ unsigned short lB[128 * 40];
  xg_body(blockIdx.x, A, Bm, bih, xg, lA, lB, threadIdx.x);
}

// ---- logits GEMM body, pre-converted bf16 B. ys is T-MAJOR: row q = t*16+b.
// Output logits row = b*128+t -> remap in epilogue (writes stay nn-contiguous). ----
__device__ __forceinline__ void final_bf_body(const int fbid,
                                              const unsigned short* __restrict__ Ay,
                                              const unsigned short* __restrict__ Bw,
                                              const float* __restrict__ obias,
                                              float* __restrict__ out,
                                              unsigned short* lA, unsigned short* lB,
                                              const int tid) {
  const int lane = tid & 63, wave = tid >> 6;
  const int wm = wave >> 1, wn = wave & 1;
  const int m0 = (fbid & 15) * 128, n0 = (fbid >> 4) * 128;  // m-fast: 16 blocks share B panel in L2
  floatx4 acc[4][4];
  #pragma unroll
  for (int i = 0; i < 4; ++i)
    #pragma unroll
    for (int jj = 0; jj < 4; ++jj) acc[i][jj] = (floatx4){0.f, 0.f, 0.f, 0.f};
  for (int kt = 0; kt < 32; ++kt) {
    const int k0 = kt * 32;
    __syncthreads();
    #pragma unroll
    for (int gi = 0; gi < 2; ++gi) {
      int gidx = tid + gi * 256;
      int r = gidx >> 2, kc = gidx & 3;
      short8 va = *(const short8*)(Ay + (size_t)(m0 + r) * H_ + k0 + kc * 8);
      *(short8*)(&lA[r * 40 + kc * 8]) = va;
      short8 vb = *(const short8*)(Bw + (size_t)(n0 + r) * H_ + k0 + kc * 8);
      *(short8*)(&lB[r * 40 + kc * 8]) = vb;
    }
    __syncthreads();
    short8 aF[4], bF[4];
    #pragma unroll
    for (int ms = 0; ms < 4; ++ms)
      aF[ms] = *(const short8*)(&lA[(wm * 64 + ms * 16 + (lane & 15)) * 40 + ((lane >> 4) << 3)]);
    #pragma unroll
    for (int ns = 0; ns < 4; ++ns)
      bF[ns] = *(const short8*)(&lB[(wn * 64 + ns * 16 + (lane & 15)) * 40 + ((lane >> 4) << 3)]);
    #pragma unroll
    for (int ms = 0; ms < 4; ++ms)
      #pragma unroll
      for (int ns = 0; ns < 4; ++ns)
        acc[ms][ns] = __builtin_amdgcn_mfma_f32_16x16x32_bf16(aF[ms], bF[ns], acc[ms][ns], 0, 0, 0);
  }
  #pragma unroll
  for (int ns = 0; ns < 4; ++ns) {
    const int nn = n0 + wn * 64 + ns * 16 + (lane & 15);
    const float bs = obias[nn];
    #pragma unroll
    for (int ms = 0; ms < 4; ++ms) {
      const int mm = m0 + wm * 64 + ms * 16 + ((lane >> 4) << 2);
      #pragma unroll
      for (int r = 0; r < 4; ++r) {
        const int q = mm + r;                         // ys row: t*16+b
        const int orow = (q & 15) * 128 + (q >> 4);   // logits row: b*128+t
        out[(size_t)orow * V_ + nn] = acc[ms][ns][r] + bs;
      }
    }
  }
}

// ---- logits GEMM, fp32-B fallback (B converted inline); runs standalone after gru(D) ----
__global__ __launch_bounds__(256) void k_final(const unsigned short* __restrict__ Ay,
                                               const float* __restrict__ Bw,
                                               const float* __restrict__ obias,
                                               float* __restrict__ out) {
  __shared__ unsigned short lA[128 * 40];
  __shared__ unsigned short lB[128 * 40];
  const int tid = threadIdx.x;
  const int lane = tid & 63, wave = tid >> 6;
  const int wm = wave >> 1, wn = wave & 1;
  const int m0 = (blockIdx.x & 15) * 128, n0 = (blockIdx.x >> 4) * 128;
  floatx4 acc[4][4];
  #pragma unroll
  for (int i = 0; i < 4; ++i)
    #pragma unroll
    for (int jj = 0; jj < 4; ++jj) acc[i][jj] = (floatx4){0.f, 0.f, 0.f, 0.f};
  for (int kt = 0; kt < 32; ++kt) {
    const int k0 = kt * 32;
    __syncthreads();
    #pragma unroll
    for (int gi = 0; gi < 2; ++gi) {
      int gidx = tid + gi * 256;
      int r = gidx >> 2, kc = gidx & 3;
      short8 va = *(const short8*)(Ay + (size_t)(m0 + r) * H_ + k0 + kc * 8);
      *(short8*)(&lA[r * 40 + kc * 8]) = va;
    }
    #pragma unroll
    for (int gi = 0; gi < 4; ++gi) {
      int gidx = tid + gi * 256;
      int r = gidx >> 3, kc = gidx & 7;
      float4 f = *(const float4*)(Bw + (size_t)(n0 + r) * H_ + k0 + kc * 4);
      union { unsigned short us[4]; unsigned long long u; } pk;
      pk.us[0] = f2bf(f.x); pk.us[1] = f2bf(f.y); pk.us[2] = f2bf(f.z); pk.us[3] = f2bf(f.w);
      *(unsigned long long*)(&lB[r * 40 + kc * 4]) = pk.u;
    }
    __syncthreads();
    short8 aF[4], bF[4];
    #pragma unroll
    for (int ms = 0; ms < 4; ++ms)
      aF[ms] = *(const short8*)(&lA[(wm * 64 + ms * 16 + (lane & 15)) * 40 + ((lane >> 4) << 3)]);
    #pragma unroll
    for (int ns = 0; ns < 4; ++ns)
      bF[ns] = *(const short8*)(&lB[(wn * 64 + ns * 16 + (lane & 15)) * 40 + ((lane >> 4) << 3)]);
    #pragma unroll
    for (int ms = 0; ms < 4; ++ms)
      #pragma unroll
      for (int ns = 0; ns < 4; ++ns)
        acc[ms][ns] = __builtin_amdgcn_mfma_f32_16x16x32_bf16(aF[ms], bF[ns], acc[ms][ns], 0, 0, 0);
  }
  #pragma unroll
  for (int ns = 0; ns < 4; ++ns) {
    const int nn = n0 + wn * 64 + ns * 16 + (lane & 15);
    const float bs = obias[nn];
    #pragma unroll
    for (int ms = 0; ms < 4; ++ms) {
      const int mm = m0 + wm * 64 + ms * 16 + ((lane >> 4) << 2);
      #pragma unroll
      for (int r = 0; r < 4; ++r) {
        const int q = mm + r;
        const int orow = (q & 15) * 128 + (q >> 4);
        out[(size_t)orow * V_ + nn] = acc[ms][ns][r] + bs;
      }
    }
  }
}

// ---- GRU recurrence body: r0's proven 64-WG gang protocol, verbatim, plus:
//  (1) s_setprio(3) so gang waves out-arbitrate co-resident GEMM waves,
//  (2) ys stored T-MAJOR via sc1 (LLC-visible to same-kernel readers on other XCDs),
//  (3) end-of-loop completion flag (T_+2) so fused GEMM tiles needing t=127 can start.
// h layout in hbuf (qwords): [buf][col4][row16]. Flags semantics: flag[j] >= s+2 means
// WG j's step-s h-publish AND ys rows t<=s are drained to the LLC (vmcnt(0) precedes flag).
__device__ __forceinline__ void gru_body(const float* __restrict__ xg,
                                         const float* __restrict__ Whh,
                                         const float* __restrict__ bhh,
                                         const float* __restrict__ h0,
                                         unsigned long long* hbuf, int* flags,
                                         float* __restrict__ hn_out,
                                         unsigned short* __restrict__ ys,
                                         float* lred, const int j, const int tid) {
  const int lane = tid & 63, wave = tid >> 6;
  const int b = tid & 15, c = tid >> 4;      // c = wave*4 + (lane>>4)
  const int hc = j * 16 + c;
  const int kbase = wave * 256;              // each wave covers a K-quarter
  __builtin_amdgcn_s_setprio(3);

  // Whh B-fragments (fp32 -> bf16) into registers, once.
  short8 bfrag[3][8];
  #pragma unroll
  for (int tau = 0; tau < 3; ++tau) {
    const float* wr = Whh + (size_t)(tau * H_ + j * 16 + (lane & 15)) * H_;
    #pragma unroll
    for (int s8 = 0; s8 < 8; ++s8) {
      int k = kbase + s8 * 32 + ((lane >> 4) << 3);
      float4 p0 = *(const float4*)(wr + k);
      float4 p1 = *(const float4*)(wr + k + 4);
      bfrag[tau][s8] = cvt8(p0, p1);
    }
  }
  const float bh0 = bhh[hc], bh1 = bhh[H_ + hc], bh2 = bhh[2 * H_ + hc];
  float h_own = h0 ? h0[b * H_ + hc] : 0.f;

  #define PACK_STORE(HVAL, BUF)                                                              \
    {                                                                                        \
      unsigned wlo = f2bf(HVAL);                                                             \
      unsigned p = wlo | (((unsigned)__shfl_xor((int)wlo, 16, 64)) << 16);                   \
      unsigned long long qv = (unsigned long long)p |                                        \
          (((unsigned long long)(unsigned)__shfl_xor((int)p, 32, 64)) << 32);                \
      if (lane < 16)                                                                         \
        __hip_atomic_store(hbuf + (size_t)(BUF) * 4096 + (j * 4 + wave) * 16 + lane, qv,     \
                           __ATOMIC_RELAXED, __HIP_MEMORY_SCOPE_AGENT);                      \
    }

  PACK_STORE(h_own, 0)
  float xr = xg[hc * 16 + b];
  float xz = xg[(H_ + hc) * 16 + b];
  float xn = xg[(2 * H_ + hc) * 16 + b];
  __syncthreads();  // drains the atomic stores (vmcnt(0) before s_barrier)
  if (tid == 0) __hip_atomic_store(flags + j, 1, __ATOMIC_RELAXED, __HIP_MEMORY_SCOPE_AGENT);
  if (wave == 0) {
    for (;;) {
      int f = __hip_atomic_load(flags + lane, __ATOMIC_RELAXED, __HIP_MEMORY_SCOPE_AGENT);
      if (__all(f >= 1)) break;   // poison 0xAAAAAAAA is negative -> safe
      __builtin_amdgcn_s_sleep(1);
    }
  }
  __syncthreads();

  for (int s = 0; s < T_; ++s) {
    const unsigned long long* src = hbuf + (size_t)(s & 1) * 4096;
    unsigned long long qa0[8], qa1[8];
    #pragma unroll
    for (int s8 = 0; s8 < 8; ++s8) {
      const int qi = (wave * 64 + s8 * 8 + ((lane >> 4) << 1)) * 16 + (lane & 15);
      qa0[s8] = __hip_atomic_load(src + qi,      __ATOMIC_RELAXED, __HIP_MEMORY_SCOPE_AGENT);
      qa1[s8] = __hip_atomic_load(src + qi + 16, __ATOMIC_RELAXED, __HIP_MEMORY_SCOPE_AGENT);
    }
    floatx4 a0 = {0.f,0.f,0.f,0.f}, a1 = {0.f,0.f,0.f,0.f}, a2 = {0.f,0.f,0.f,0.f};
    #pragma unroll
    for (int s8 = 0; s8 < 8; ++s8) {
      union { unsigned long long q[2]; short8 v; } u;
      u.q[0] = qa0[s8]; u.q[1] = qa1[s8];
      a0 = __builtin_amdgcn_mfma_f32_16x16x32_bf16(u.v, bfrag[0][s8], a0, 0, 0, 0);
      a1 = __builtin_amdgcn_mfma_f32_16x16x32_bf16(u.v, bfrag[1][s8], a1, 0, 0, 0);
      a2 = __builtin_amdgcn_mfma_f32_16x16x32_bf16(u.v, bfrag[2][s8], a2, 0, 0, 0);
    }
    {
      int pb = wave * 768 + (lane & 15) * 16 + ((lane >> 4) << 2);
      *(floatx4*)(&lred[pb])       = a0;
      *(floatx4*)(&lred[pb + 256]) = a1;
      *(floatx4*)(&lred[pb + 512]) = a2;
    }
    __syncthreads();
    float g0 = bh0, g1 = bh1, g2 = bh2;
    #pragma unroll
    for (int wv = 0; wv < 4; ++wv) {
      int rb = wv * 768 + c * 16 + b;
      g0 += lred[rb]; g1 += lred[rb + 256]; g2 += lred[rb + 512];
    }
    const float rg = 1.f / (1.f + expf(-(xr + g0)));
    const float zg = 1.f / (1.f + expf(-(xz + g1)));
    const float ng = tanhf(xn + rg * g2);
    const float hnew = (1.f - zg) * ng + zg * h_own;
    h_own = hnew;
    if (ys) st2_sc1(ys + (size_t)(s * 16 + b) * H_ + hc, f2bf(hnew));  // T-major, LLC-visible
    PACK_STORE(hnew, (s + 1) & 1)
    if (s < T_ - 1) {
      const float* xgn = xg + (size_t)(s + 1) * (G3_ * 16);
      float xrN = xgn[hc * 16 + b];
      float xzN = xgn[(H_ + hc) * 16 + b];
      float xnN = xgn[(2 * H_ + hc) * 16 + b];
      __syncthreads();  // drains this step's h + ys stores
      if (tid == 0) __hip_atomic_store(flags + j, s + 2, __ATOMIC_RELAXED, __HIP_MEMORY_SCOPE_AGENT);
      if (wave == 0) {
        for (;;) {
          int f = __hip_atomic_load(flags + lane, __ATOMIC_RELAXED, __HIP_MEMORY_SCOPE_AGENT);
          if (__all(f >= s + 2)) break;
          __builtin_amdgcn_s_sleep(1);
        }
      }
      __syncthreads();
      xr = xrN; xz = xzN; xn = xnN;
    }
  }
  __syncthreads();  // drain final step's ys stores before the completion flag
  if (tid == 0) __hip_atomic_store(flags + j, T_ + 2, __ATOMIC_RELAXED, __HIP_MEMORY_SCOPE_AGENT);
  if (hn_out) hn_out[b * H_ + hc] = h_own;
  #undef PACK_STORE
}

// ---- fused encoder dispatch: gang (bid<64) + xg(D) GEMM (64..447) + out_W cvt (448..959) ----
__global__ __launch_bounds__(256, 1) void k_gruE_fused(
    const float* __restrict__ xg, const float* __restrict__ Whh,
    const float* __restrict__ bhh,
    unsigned long long* hbuf, int* flags, float* __restrict__ hn_out,
    const unsigned short* __restrict__ A2, const unsigned short* __restrict__ B2,
    const float* __restrict__ bih2, float* __restrict__ xg2,
    const float* __restrict__ cvsrc, unsigned short* __restrict__ cvdst, int n4) {
  __shared__ float lred[3072];
  __shared__ unsigned short lA[128 * 40];
  __shared__ unsigned short lB[128 * 40];
  const int tid = threadIdx.x;
  const int bid = blockIdx.x;
  if (bid < 64) {
    gru_body(xg, Whh, bhh, nullptr, hbuf, flags, hn_out, nullptr, lred, bid, tid);
  } else if (bid < 448) {
    xg_body(bid - 64, A2, B2, bih2, xg2, lA, lB, tid);
  } else {
    int i = (bid - 448) * 256 + tid;
    const int stride = 512 * 256;
    for (; i < n4; i += stride) {
      float4 f = ((const float4*)cvsrc)[i];
      union { unsigned short us[4]; unsigned long long u; } pk;
      pk.us[0] = f2bf(f.x); pk.us[1] = f2bf(f.y); pk.us[2] = f2bf(f.z); pk.us[3] = f2bf(f.w);
      ((unsigned long long*)cvdst)[i] = pk.u;
    }
  }
}

// ---- fused decoder dispatch: gang (bid<64) + 4000 logits-GEMM tiles that start as soon
// as the ys rows they need are published (flags[*] >= tmax+2). Gang dispatched first ->
// always resident; GEMM tiles only WAIT on gang progress (acyclic -> deadlock-free). ----
__global__ __launch_bounds__(256, 1) void k_gruD_fused(
    const float* __restrict__ xg, const float* __restrict__ Whh,
    const float* __restrict__ bhh, const float* __restrict__ h0,
    unsigned long long* hbuf, int* flags, unsigned short* __restrict__ ys,
    const unsigned short* __restrict__ Bw, const float* __restrict__ obias,
    float* __restrict__ out) {
  __shared__ float lred[3072];
  __shared__ unsigned short lA[128 * 40];
  __shared__ unsigned short lB[128 * 40];
  const int tid = threadIdx.x;
  const int bid = blockIdx.x;
  if (bid < 64) {
    gru_body(xg, Whh, bhh, h0, hbuf, flags, nullptr, ys, lred, bid, tid);
  } else {
    const int fbid = bid - 64;
    const int need = (fbid & 15) * 8 + 9;    // tmax = (fbid&15)*8+7 -> flag >= tmax+2
    if (tid < 64) {
      for (;;) {
        int f = __hip_atomic_load(flags + tid, __ATOMIC_RELAXED, __HIP_MEMORY_SCOPE_AGENT);
        if (__all(f >= need)) break;         // poison negative -> waits correctly
        __builtin_amdgcn_s_sleep(127);       // gentle poll: ~8k cycles backoff
      }
    }
    __syncthreads();
    final_bf_body(fbid, ys, Bw, obias, out, lA, lB, tid);
  }
}

// ---- VAE heads: mu/logvar/style/content (+ cat buffer for fc). One wave per (b,o). ----
__global__ void k_heads(const float* __restrict__ hn,
                        const float* __restrict__ musW, const float* __restrict__ musb,
                        const float* __restrict__ varsW, const float* __restrict__ varsb,
                        const float* __restrict__ mucW, const float* __restrict__ mucb,
                        const float* __restrict__ varcW, const float* __restrict__ varcb,
                        const float* __restrict__ eps_s, const float* __restrict__ eps_c,
                        float* __restrict__ out, float* __restrict__ cat) {
  const int wv = blockIdx.x * 4 + (threadIdx.x >> 6);
  const int lane = threadIdx.x & 63;
  const int b = wv >> 8, o = wv & 255;
  const float* h = hn + (size_t)b * H_;
  const float *w1, *w2; float bb1, bb2, ep; int oc = 0;
  const int smode = (o < 64);
  if (smode) { w1 = musW + (size_t)o * H_;  w2 = varsW + (size_t)o * H_;  bb1 = musb[o];  bb2 = varsb[o];  ep = eps_s[b * 64 + o]; }
  else { oc = o - 64; w1 = mucW + (size_t)oc * H_; w2 = varcW + (size_t)oc * H_; bb1 = mucb[oc]; bb2 = varcb[oc]; ep = eps_c[b * 192 + oc]; }
  float s1 = 0.f, s2 = 0.f;
  #pragma unroll
  for (int i = 0; i < 4; ++i) {
    int k = lane * 4 + i * 256;
    float4 hv = *(const float4*)(h + k);
    float4 av = *(const float4*)(w1 + k);
    float4 bv = *(const float4*)(w2 + k);
    s1 += dot4(hv, av); s2 += dot4(hv, bv);
  }
  s1 = wsum(s1); s2 = wsum(s2);
  if (lane == 0) {
    const float mu = s1 + bb1, lv = s2 + bb2;
    const float sc = mu + ep * expf(0.5f * lv);
    if (smode) {
      out[OF_MUS + b * 64 + o] = mu;
      out[OF_LVS + b * 64 + o] = lv;
      out[OF_STYLE + b * 64 + o] = sc;
      cat[b * 256 + o] = sc;
    } else {
      out[OF_MUC + b * 192 + oc] = mu;
      out[OF_LVC + b * 192 + oc] = lv;
      out[OF_CONTENT + b * 192 + oc] = sc;
      cat[b * 256 + 64 + oc] = sc;
    }
  }
}

// ---- z = cat @ fc_W^T + fc_b : one wave per (b,h), K=256 = 64 lanes x float4 ----
__global__ void k_z(const float* __restrict__ cat, const float* __restrict__ fcW,
                    const float* __restrict__ fcb, float* __restrict__ z) {
  const int wv = blockIdx.x * 4 + (threadIdx.x >> 6);
  const int lane = threadIdx.x & 63;
  const int b = wv >> 10, h = wv & 1023;
  float4 a = *(const float4*)(cat + b * 256 + lane * 4);
  float4 w = *(const float4*)(fcW + (size_t)h * 256 + lane * 4);
  float p = dot4(a, w);
  p = wsum(p);
  if (lane == 0) z[b * H_ + h] = p + fcb[h];
}

extern "C" void kernel_launch(void* const* d_in, const int* in_sizes, int n_in,
                              void* d_out, int out_size, void* d_ws, size_t ws_size,
                              hipStream_t stream) {
  (void)in_sizes; (void)n_in; (void)out_size;
  const int*   x       = (const int*)d_in[0];
  const int*   sos     = (const int*)d_in[1];
  const float* eps_s   = (const float*)d_in[2];
  const float* eps_c   = (const float*)d_in[3];
  const float* emb     = (const float*)d_in[4];
  const float* ln_g    = (const float*)d_in[5];
  const float* ln_b    = (const float*)d_in[6];
  const float* enc_Wih = (const float*)d_in[7];
  const float* enc_Whh = (const float*)d_in[8];
  const float* enc_bih = (const float*)d_in[9];
  const float* enc_bhh = (const float*)d_in[10];
  const float* mus_W   = (const float*)d_in[11];
  const float* mus_b   = (const float*)d_in[12];
  const float* vars_W  = (const float*)d_in[13];
  const float* vars_b  = (const float*)d_in[14];
  const float* muc_W   = (const float*)d_in[15];
  const float* muc_b   = (const float*)d_in[16];
  const float* varc_W  = (const float*)d_in[17];
  const float* varc_b  = (const float*)d_in[18];
  const float* fc_W    = (const float*)d_in[19];
  const float* fc_b    = (const float*)d_in[20];
  const float* dec_Wih = (const float*)d_in[21];
  const float* dec_Whh = (const float*)d_in[22];
  const float* dec_bih = (const float*)d_in[23];
  const float* dec_bhh = (const float*)d_in[24];
  const float* out_W   = (const float*)d_in[25];
  const float* out_b   = (const float*)d_in[26];
  float* out = (float*)d_out;

  char* w = (char*)d_ws;
  unsigned short* e2   = (unsigned short*)(w + 0);          // 1,310,720
  unsigned short* de2  = (unsigned short*)(w + 1310720);    // 1,310,720
  unsigned short* wihE = (unsigned short*)(w + 2621440);    // 1,966,080
  unsigned short* wihD = (unsigned short*)(w + 4587520);    // 1,966,080
  float* xgE           = (float*)(w + 6553600);             // 25,165,824
  float* xgD           = (float*)(w + 31719424);            // 25,165,824
  unsigned short* ys   = (unsigned short*)(w + 56885248);   // 4,194,304 (T-major rows t*16+b)
  unsigned long long* hbuf = (unsigned long long*)(w + 61079552);  // 65,536
  float* hn            = (float*)(w + 61145088);            // 65,536
  float* zb            = (float*)(w + 61210624);            // 65,536
  float* catb          = (float*)(w + 61276160);            // 16,384
  int* flagsE          = (int*)(w + 61292544);              // 256
  int* flagsD          = flagsE + 64;                       // 256
  unsigned short* woutBf = (unsigned short*)(w + 61293056); // 65,536,000 (optional)
  const bool bigws = (ws_size >= 126829056ull);

  k_wih<<<960, 256, 0, stream>>>(enc_Wih, wihE);
  k_wih<<<960, 256, 0, stream>>>(dec_Wih, wihD);
  k_embed<<<513, 256, 0, stream>>>(x, sos, emb, ln_g, ln_b, e2, de2);
  k_xg<<<384, 256, 0, stream>>>(wihE, e2, enc_bih, xgE);
  // encoder recurrence + (hidden underneath it) decoder-xg GEMM and out_W conversion
  k_gruE_fused<<<bigws ? 960 : 448, 256, 0, stream>>>(
      xgE, enc_Whh, enc_bhh, hbuf, flagsE, hn,
      wihD, de2, dec_bih, xgD,
      out_W, bigws ? woutBf : (unsigned short*)nullptr, V_ * H_ / 4);
  k_heads<<<1024, 256, 0, stream>>>(hn, mus_W, mus_b, vars_W, vars_b,
                                    muc_W, muc_b, varc_W, varc_b, eps_s, eps_c, out, catb);
  k_z<<<4096, 256, 0, stream>>>(catb, fc_W, fc_b, zb);
  if (bigws) {
    // decoder recurrence + logits GEMM pipelined against ys production
    k_gruD_fused<<<64 + 4000, 256, 0, stream>>>(
        xgD, dec_Whh, dec_bhh, zb, hbuf, flagsD, ys, woutBf, out_b, out);
  } else {
    k_gruD_fused<<<64, 256, 0, stream>>>(
        xgD, dec_Whh, dec_bhh, zb, hbuf, flagsD, ys,
        (const unsigned short*)nullptr, out_b, out);
    k_final<<<4000, 256, 0, stream>>>(ys, out_W, out_b, out);
  }
}